// Round 3
// baseline (12972.490 us; speedup 1.0000x reference)
//
#include <hip/hip_runtime.h>

#define NN 8192
#define DD 32
#define REGV_INV 10.0f
#define KSCALE 512.0f
#define RCH 32      // rows per mv chunk
#define CCH 2048    // cols per mv block (bytes == fp8 elems)

typedef unsigned int uint;
typedef unsigned char uchar;
typedef float vfloat2 __attribute__((ext_vector_type(2)));

static __device__ __forceinline__ uint pack4_fp8(float a, float b, float c, float d) {
  uint v = 0;
  v = __builtin_amdgcn_cvt_pk_fp8_f32(a, b, v, false);
  v = __builtin_amdgcn_cvt_pk_fp8_f32(c, d, v, true);
  return v;
}

static __device__ __forceinline__ void fma4_fp8(uint q, float ur, float* a) {
  vfloat2 lo = __builtin_amdgcn_cvt_pk_f32_fp8(q, false);
  vfloat2 hi = __builtin_amdgcn_cvt_pk_f32_fp8(q, true);
  a[0] = fmaf(lo.x, ur, a[0]);
  a[1] = fmaf(lo.y, ur, a[1]);
  a[2] = fmaf(hi.x, ur, a[2]);
  a[3] = fmaf(hi.y, ur, a[3]);
}

static __device__ __forceinline__ void atomAddF(float* p, float v) {
#if defined(__has_builtin)
#if __has_builtin(__hip_atomic_fetch_add)
  __hip_atomic_fetch_add(p, v, __ATOMIC_RELAXED, __HIP_MEMORY_SCOPE_AGENT);
#else
  atomicAdd(p, v);
#endif
#else
  atomicAdd(p, v);
#endif
}

// ---------------- softmax over 8192 elements (one block per array) ----------------
__global__ __launch_bounds__(1024) void softmax_k(const float* __restrict__ A,
                                                  const float* __restrict__ B,
                                                  float* __restrict__ mu,
                                                  float* __restrict__ nu) {
  const float* in = (blockIdx.x == 0) ? A : B;
  float* out = (blockIdx.x == 0) ? mu : nu;
  int tid = threadIdx.x;
  float v[8];
  float m = -1e30f;
#pragma unroll
  for (int k = 0; k < 8; k++) { v[k] = in[tid + k * 1024]; m = fmaxf(m, v[k]); }
#pragma unroll
  for (int o = 1; o < 64; o <<= 1) m = fmaxf(m, __shfl_xor(m, o));
  __shared__ float red[16];
  __shared__ float bval;
  int wid = tid >> 6, lane = tid & 63;
  if (lane == 0) red[wid] = m;
  __syncthreads();
  if (tid == 0) { float t = red[0]; for (int k = 1; k < 16; k++) t = fmaxf(t, red[k]); bval = t; }
  __syncthreads();
  m = bval;
  float e[8]; float s = 0.f;
#pragma unroll
  for (int k = 0; k < 8; k++) { e[k] = __expf(v[k] - m); s += e[k]; }
#pragma unroll
  for (int o = 1; o < 64; o <<= 1) s += __shfl_xor(s, o);
  __syncthreads();
  if (lane == 0) red[wid] = s;
  __syncthreads();
  if (tid == 0) { float t = 0.f; for (int k = 0; k < 16; k++) t += red[k]; bval = t; }
  __syncthreads();
  float inv = 1.0f / bval;
#pragma unroll
  for (int k = 0; k < 8; k++) out[tid + k * 1024] = e[k] * inv;
}

// ---------------- zero the 3 rotating sum buffers (3*NN floats, contiguous) ----------------
__global__ __launch_bounds__(1024) void zero3_k(float* __restrict__ z) {
  int i = blockIdx.x * 1024 + threadIdx.x;
  if (i < 3 * NN) z[i] = 0.f;
}

// ---------------- build K (row-major) and KT (transpose), fp8 e4m3 scaled by KSCALE ----------------
__global__ __launch_bounds__(256) void build8_k(const float* __restrict__ X,
                                                const float* __restrict__ Y,
                                                uchar* __restrict__ K,
                                                uchar* __restrict__ KT) {
  __shared__ float lx[32][DD];
  __shared__ float lx2[32];
  __shared__ __align__(16) uchar lkb[32][256];
  int tid = threadIdx.x;
  int rb = (blockIdx.x >> 5) * 32;
  int cb = (blockIdx.x & 31) * 256;
  {
    int r = tid >> 3, dq = (tid & 7) * 4;
    float4 vv = *(const float4*)&X[(size_t)(rb + r) * DD + dq];
    lx[r][dq] = vv.x; lx[r][dq + 1] = vv.y; lx[r][dq + 2] = vv.z; lx[r][dq + 3] = vv.w;
  }
  __syncthreads();
  if (tid < 32) {
    float s = 0.f;
#pragma unroll
    for (int d = 0; d < DD; d++) s = fmaf(lx[tid][d], lx[tid][d], s);
    lx2[tid] = s;
  }
  int j = cb + tid;
  float yv[DD]; float y2 = 0.f;
#pragma unroll
  for (int dq = 0; dq < DD; dq += 4) {
    float4 vv = *(const float4*)&Y[(size_t)j * DD + dq];
    yv[dq] = vv.x; yv[dq + 1] = vv.y; yv[dq + 2] = vv.z; yv[dq + 3] = vv.w;
    y2 = fmaf(vv.x, vv.x, fmaf(vv.y, vv.y, fmaf(vv.z, vv.z, fmaf(vv.w, vv.w, y2))));
  }
  __syncthreads();
  float kv[32];
#pragma unroll
  for (int r = 0; r < 32; r++) {
    float dot = 0.f;
#pragma unroll
    for (int dq = 0; dq < DD; dq += 4) {
      float4 xx = *(const float4*)&lx[r][dq];
      dot = fmaf(xx.x, yv[dq], fmaf(xx.y, yv[dq + 1], fmaf(xx.z, yv[dq + 2], fmaf(xx.w, yv[dq + 3], dot))));
    }
    float d2 = lx2[r] + y2 - 2.0f * dot;
    float Mv = sqrtf(fmaxf(d2, 1e-12f));
    float kk = fminf(__expf(-Mv * REGV_INV) * KSCALE, 448.f);
    kv[r] = kk;
    lkb[r][tid] = (uchar)(pack4_fp8(kk, 0.f, 0.f, 0.f) & 0xffu);
  }
  {
    // KT: thread owns column j -> contiguous 32 bytes of KT row j
    uint w0 = pack4_fp8(kv[0], kv[1], kv[2], kv[3]);
    uint w1 = pack4_fp8(kv[4], kv[5], kv[6], kv[7]);
    uint w2 = pack4_fp8(kv[8], kv[9], kv[10], kv[11]);
    uint w3 = pack4_fp8(kv[12], kv[13], kv[14], kv[15]);
    uint w4 = pack4_fp8(kv[16], kv[17], kv[18], kv[19]);
    uint w5 = pack4_fp8(kv[20], kv[21], kv[22], kv[23]);
    uint w6 = pack4_fp8(kv[24], kv[25], kv[26], kv[27]);
    uint w7 = pack4_fp8(kv[28], kv[29], kv[30], kv[31]);
    uint4* dst = (uint4*)&KT[(size_t)j * NN + rb];
    dst[0] = make_uint4(w0, w1, w2, w3);
    dst[1] = make_uint4(w4, w5, w6, w7);
  }
  __syncthreads();
  {
    int r = tid >> 3, seg = tid & 7;
    const uint4* src = (const uint4*)&lkb[r][seg * 32];
    uint4* dstk = (uint4*)&K[(size_t)(rb + r) * NN + cb + seg * 32];
    dstk[0] = src[0];
    dstk[1] = src[1];
  }
}

// ---------------- fp8 matvec with direct atomic column-sum accumulation ----------------
// outsum[j] += sum_{rows in rc} mat[row][j] * u[row],  u[row] = init ? 1/N : w[row]/insum[row]
// grid = 4 col-chunks x 256 row-chunks = 1024 blocks; 8 cols/thread (uint2, 8B/lane)
__global__ __launch_bounds__(256) void mv8_k(const uchar* __restrict__ mat,
                                             const float* __restrict__ insum,
                                             const float* __restrict__ w,
                                             float* __restrict__ outsum,
                                             float* __restrict__ zsum,
                                             int init) {
  int tid = threadIdx.x;
  int bid = blockIdx.x;
  int cc = bid & 3;
  int rc = bid >> 2;
  __shared__ float lu[RCH];
  if (tid < 8) zsum[bid * 8 + tid] = 0.f;   // zero the buffer dispatch d+2 accumulates into
  if (tid < RCH) {
    int i = rc * RCH + tid;
    lu[tid] = init ? (1.0f / NN) : (w[i] / insum[i]);
  }
  __syncthreads();
  const uint2* m2 = (const uint2*)(mat + (size_t)rc * RCH * NN + (size_t)cc * CCH);
  float a[8] = {0.f, 0.f, 0.f, 0.f, 0.f, 0.f, 0.f, 0.f};
#pragma unroll
  for (int r = 0; r < RCH; r++) {
    uint2 q = m2[(size_t)r * (NN / 8) + tid];
    float ur = lu[r];
    fma4_fp8(q.x, ur, a);
    fma4_fp8(q.y, ur, a + 4);
  }
  float* outp = outsum + cc * CCH + tid * 8;
#pragma unroll
  for (int k = 0; k < 8; k++) atomAddF(&outp[k], a[k]);
}

// ---------------- final u,v from the last two sum buffers ----------------
__global__ __launch_bounds__(256) void uv_k(const float* __restrict__ Tsum,
                                            const float* __restrict__ Ssum,
                                            const float* __restrict__ mu,
                                            const float* __restrict__ nu,
                                            float* __restrict__ uarr,
                                            float* __restrict__ varr) {
  int b = blockIdx.x;
  int i = (b & 31) * 256 + threadIdx.x;
  if (b < 32) uarr[i] = mu[i] / Tsum[i];
  else varr[i] = nu[i] / Ssum[i];
}

// ---------------- final loss: sum_ij u_i K'_ij M_ij v_j, K' recomputed (exp + fp8 round-trip) ----------------
__global__ __launch_bounds__(256) void loss_k(const float* __restrict__ X, const float* __restrict__ Y,
                                              const float* __restrict__ uarr, const float* __restrict__ varr,
                                              float* __restrict__ part) {
  int tid = threadIdx.x;
  int rb = (int)(blockIdx.x >> 4) * 128;
  int cb = (int)(blockIdx.x & 15) * 512;
  __shared__ float lx[128][DD];
  __shared__ float lx2[128];
  __shared__ float lu[128];
#pragma unroll
  for (int q = 0; q < 4; q++) {
    int idx = tid + q * 256;
    int r = idx >> 3, dq = (idx & 7) * 4;
    float4 vv = *(const float4*)&X[(size_t)(rb + r) * DD + dq];
    lx[r][dq] = vv.x; lx[r][dq + 1] = vv.y; lx[r][dq + 2] = vv.z; lx[r][dq + 3] = vv.w;
  }
  __syncthreads();
  if (tid < 128) {
    float s = 0.f;
#pragma unroll
    for (int d = 0; d < DD; d++) s = fmaf(lx[tid][d], lx[tid][d], s);
    lx2[tid] = s;
    lu[tid] = uarr[rb + tid];
  }
  int j0 = cb + tid * 2;
  float yv0[DD], yv1[DD]; float y20 = 0.f, y21 = 0.f;
#pragma unroll
  for (int dq = 0; dq < DD; dq += 4) {
    float4 a = *(const float4*)&Y[(size_t)j0 * DD + dq];
    float4 b = *(const float4*)&Y[(size_t)(j0 + 1) * DD + dq];
    yv0[dq] = a.x; yv0[dq + 1] = a.y; yv0[dq + 2] = a.z; yv0[dq + 3] = a.w;
    y20 = fmaf(a.x, a.x, fmaf(a.y, a.y, fmaf(a.z, a.z, fmaf(a.w, a.w, y20))));
    yv1[dq] = b.x; yv1[dq + 1] = b.y; yv1[dq + 2] = b.z; yv1[dq + 3] = b.w;
    y21 = fmaf(b.x, b.x, fmaf(b.y, b.y, fmaf(b.z, b.z, fmaf(b.w, b.w, y21))));
  }
  float v0 = varr[j0], v1 = varr[j0 + 1];
  __syncthreads();
  float acc = 0.f;
  for (int r = 0; r < 128; r++) {
    float dot0 = 0.f, dot1 = 0.f;
#pragma unroll
    for (int dq = 0; dq < DD; dq += 4) {
      float4 xx = *(const float4*)&lx[r][dq];
      dot0 = fmaf(xx.x, yv0[dq], fmaf(xx.y, yv0[dq + 1], fmaf(xx.z, yv0[dq + 2], fmaf(xx.w, yv0[dq + 3], dot0))));
      dot1 = fmaf(xx.x, yv1[dq], fmaf(xx.y, yv1[dq + 1], fmaf(xx.z, yv1[dq + 2], fmaf(xx.w, yv1[dq + 3], dot1))));
    }
    float d20 = lx2[r] + y20 - 2.0f * dot0;
    float d21 = lx2[r] + y21 - 2.0f * dot1;
    float M0 = sqrtf(fmaxf(d20, 1e-12f));
    float M1 = sqrtf(fmaxf(d21, 1e-12f));
    float k0 = fminf(__expf(-M0 * REGV_INV) * KSCALE, 448.f);
    float k1 = fminf(__expf(-M1 * REGV_INV) * KSCALE, 448.f);
    uint e = pack4_fp8(k0, k1, 0.f, 0.f);
    vfloat2 kk = __builtin_amdgcn_cvt_pk_f32_fp8(e, false);
    acc = fmaf(lu[r], kk.x * M0 * v0 + kk.y * M1 * v1, acc);
  }
#pragma unroll
  for (int o = 1; o < 64; o <<= 1) acc += __shfl_xor(acc, o);
  __shared__ float r4[4];
  if ((tid & 63) == 0) r4[tid >> 6] = acc;
  __syncthreads();
  if (tid == 0) part[blockIdx.x] = r4[0] + r4[1] + r4[2] + r4[3];
}

__global__ __launch_bounds__(256) void finish_k(const float* __restrict__ part, float* __restrict__ out) {
  int tid = threadIdx.x;
  float s = 0.f;
  for (int k = tid; k < 1024; k += 256) s += part[k];
#pragma unroll
  for (int o = 1; o < 64; o <<= 1) s += __shfl_xor(s, o);
  __shared__ float r4[4];
  if ((tid & 63) == 0) r4[tid >> 6] = s;
  __syncthreads();
  if (tid == 0) out[0] = r4[0] + r4[1] + r4[2] + r4[3];
}

extern "C" void kernel_launch(void* const* d_in, const int* in_sizes, int n_in,
                              void* d_out, int out_size, void* d_ws, size_t ws_size,
                              hipStream_t stream) {
  const float* X = (const float*)d_in[0];
  const float* Y = (const float*)d_in[1];
  const float* sd = (const float*)d_in[2];
  const float* td = (const float*)d_in[3];
  float* out = (float*)d_out;

  char* p = (char*)d_ws;
  uchar* K = (uchar*)p; p += (size_t)NN * NN;          // 67.1 MB
  uchar* KT = (uchar*)p; p += (size_t)NN * NN;         // 67.1 MB
  float* mu = (float*)p; p += (size_t)NN * 4;
  float* nu = (float*)p; p += (size_t)NN * 4;
  float* uarr = (float*)p; p += (size_t)NN * 4;
  float* varr = (float*)p; p += (size_t)NN * 4;
  float* sums = (float*)p; p += (size_t)3 * NN * 4;    // 3 rotating sum buffers
  float* part = (float*)p;                             // 4 KB

  float* bufs[3] = { sums, sums + NN, sums + 2 * NN };

  softmax_k<<<2, 1024, 0, stream>>>(sd, td, mu, nu);
  zero3_k<<<24, 1024, 0, stream>>>(sums);
  build8_k<<<8192, 256, 0, stream>>>(X, Y, K, KT);

  // dispatch d: even -> s_j = sum_i K_ij u_i (u = mu/Tsum), odd -> t_i = sum_j K_ij v_j (v = nu/Ssum)
  for (int d = 0; d < 200; d++) {
    const uchar* mat = (d & 1) ? KT : K;
    const float* w = (d & 1) ? nu : mu;
    mv8_k<<<1024, 256, 0, stream>>>(mat, bufs[(d + 2) % 3], w, bufs[d % 3], bufs[(d + 1) % 3], d == 0 ? 1 : 0);
  }

  // after d=199: T-sums in bufs[199%3=1], S-sums in bufs[198%3=0]
  uv_k<<<64, 256, 0, stream>>>(bufs[1], bufs[0], mu, nu, uarr, varr);
  loss_k<<<1024, 256, 0, stream>>>(X, Y, uarr, varr, part);
  finish_k<<<1, 256, 0, stream>>>(part, out);
}

// Round 4
// 3092.338 us; speedup vs baseline: 4.1950x; 4.1950x over previous
//
#include <hip/hip_runtime.h>

#define NN 8192
#define DD 32
#define REGV_INV 10.0f
#define KSCALE 512.0f
#define RCH 128     // rows per mv chunk (reduction dim)
#define NPART 64    // = NN / RCH
#define CCH 2048    // cols per mv block

typedef unsigned int uint;
typedef unsigned char uchar;
typedef float vfloat2 __attribute__((ext_vector_type(2)));

static __device__ __forceinline__ uint pack4_fp8(float a, float b, float c, float d) {
  uint v = 0;
  v = __builtin_amdgcn_cvt_pk_fp8_f32(a, b, v, false);
  v = __builtin_amdgcn_cvt_pk_fp8_f32(c, d, v, true);
  return v;
}

static __device__ __forceinline__ void fma4_fp8(uint q, float ur, float* a) {
  vfloat2 lo = __builtin_amdgcn_cvt_pk_f32_fp8(q, false);
  vfloat2 hi = __builtin_amdgcn_cvt_pk_f32_fp8(q, true);
  a[0] = fmaf(lo.x, ur, a[0]);
  a[1] = fmaf(lo.y, ur, a[1]);
  a[2] = fmaf(hi.x, ur, a[2]);
  a[3] = fmaf(hi.y, ur, a[3]);
}

// ---------------- softmax over 8192 elements (one block per array) ----------------
__global__ __launch_bounds__(1024) void softmax_k(const float* __restrict__ A,
                                                  const float* __restrict__ B,
                                                  float* __restrict__ mu,
                                                  float* __restrict__ nu) {
  const float* in = (blockIdx.x == 0) ? A : B;
  float* out = (blockIdx.x == 0) ? mu : nu;
  int tid = threadIdx.x;
  float v[8];
  float m = -1e30f;
#pragma unroll
  for (int k = 0; k < 8; k++) { v[k] = in[tid + k * 1024]; m = fmaxf(m, v[k]); }
#pragma unroll
  for (int o = 1; o < 64; o <<= 1) m = fmaxf(m, __shfl_xor(m, o));
  __shared__ float red[16];
  __shared__ float bval;
  int wid = tid >> 6, lane = tid & 63;
  if (lane == 0) red[wid] = m;
  __syncthreads();
  if (tid == 0) { float t = red[0]; for (int k = 1; k < 16; k++) t = fmaxf(t, red[k]); bval = t; }
  __syncthreads();
  m = bval;
  float e[8]; float s = 0.f;
#pragma unroll
  for (int k = 0; k < 8; k++) { e[k] = __expf(v[k] - m); s += e[k]; }
#pragma unroll
  for (int o = 1; o < 64; o <<= 1) s += __shfl_xor(s, o);
  __syncthreads();
  if (lane == 0) red[wid] = s;
  __syncthreads();
  if (tid == 0) { float t = 0.f; for (int k = 0; k < 16; k++) t += red[k]; bval = t; }
  __syncthreads();
  float inv = 1.0f / bval;
#pragma unroll
  for (int k = 0; k < 8; k++) out[tid + k * 1024] = e[k] * inv;
}

// ---------------- build K (row-major) and KT (transpose), fp8 e4m3 scaled by KSCALE ----------------
__global__ __launch_bounds__(256) void build8_k(const float* __restrict__ X,
                                                const float* __restrict__ Y,
                                                uchar* __restrict__ K,
                                                uchar* __restrict__ KT) {
  __shared__ float lx[32][DD];
  __shared__ float lx2[32];
  __shared__ __align__(16) uchar lkb[32][256];
  int tid = threadIdx.x;
  int rb = (blockIdx.x >> 5) * 32;
  int cb = (blockIdx.x & 31) * 256;
  {
    int r = tid >> 3, dq = (tid & 7) * 4;
    float4 vv = *(const float4*)&X[(size_t)(rb + r) * DD + dq];
    lx[r][dq] = vv.x; lx[r][dq + 1] = vv.y; lx[r][dq + 2] = vv.z; lx[r][dq + 3] = vv.w;
  }
  __syncthreads();
  if (tid < 32) {
    float s = 0.f;
#pragma unroll
    for (int d = 0; d < DD; d++) s = fmaf(lx[tid][d], lx[tid][d], s);
    lx2[tid] = s;
  }
  int j = cb + tid;
  float yv[DD]; float y2 = 0.f;
#pragma unroll
  for (int dq = 0; dq < DD; dq += 4) {
    float4 vv = *(const float4*)&Y[(size_t)j * DD + dq];
    yv[dq] = vv.x; yv[dq + 1] = vv.y; yv[dq + 2] = vv.z; yv[dq + 3] = vv.w;
    y2 = fmaf(vv.x, vv.x, fmaf(vv.y, vv.y, fmaf(vv.z, vv.z, fmaf(vv.w, vv.w, y2))));
  }
  __syncthreads();
  float kv[32];
#pragma unroll
  for (int r = 0; r < 32; r++) {
    float dot = 0.f;
#pragma unroll
    for (int dq = 0; dq < DD; dq += 4) {
      float4 xx = *(const float4*)&lx[r][dq];
      dot = fmaf(xx.x, yv[dq], fmaf(xx.y, yv[dq + 1], fmaf(xx.z, yv[dq + 2], fmaf(xx.w, yv[dq + 3], dot))));
    }
    float d2 = lx2[r] + y2 - 2.0f * dot;
    float Mv = sqrtf(fmaxf(d2, 1e-12f));
    float kk = fminf(__expf(-Mv * REGV_INV) * KSCALE, 448.f);
    kv[r] = kk;
    lkb[r][tid] = (uchar)(pack4_fp8(kk, 0.f, 0.f, 0.f) & 0xffu);
  }
  {
    // KT: thread owns column j -> contiguous 32 bytes of KT row j
    uint w0 = pack4_fp8(kv[0], kv[1], kv[2], kv[3]);
    uint w1 = pack4_fp8(kv[4], kv[5], kv[6], kv[7]);
    uint w2 = pack4_fp8(kv[8], kv[9], kv[10], kv[11]);
    uint w3 = pack4_fp8(kv[12], kv[13], kv[14], kv[15]);
    uint w4 = pack4_fp8(kv[16], kv[17], kv[18], kv[19]);
    uint w5 = pack4_fp8(kv[20], kv[21], kv[22], kv[23]);
    uint w6 = pack4_fp8(kv[24], kv[25], kv[26], kv[27]);
    uint w7 = pack4_fp8(kv[28], kv[29], kv[30], kv[31]);
    uint4* dst = (uint4*)&KT[(size_t)j * NN + rb];
    dst[0] = make_uint4(w0, w1, w2, w3);
    dst[1] = make_uint4(w4, w5, w6, w7);
  }
  __syncthreads();
  {
    int r = tid >> 3, seg = tid & 7;
    const uint4* src = (const uint4*)&lkb[r][seg * 32];
    uint4* dstk = (uint4*)&K[(size_t)(rb + r) * NN + cb + seg * 32];
    dstk[0] = src[0];
    dstk[1] = src[1];
  }
}

// ---------------- fp8 partialized matvec ----------------
// out_part[rc][j] = sum_{i in rc's 128 rows} mat[i][j] * u[i]
// u[i] = init ? 1/N : w[i] / sum_p in_part[p][i]
// grid = 64 row-chunks x 4 col-chunks = 256 blocks, 256 threads, 8 cols/thread (uint2)
__global__ __launch_bounds__(256) void mv8_k(const uchar* __restrict__ mat,
                                             const float* __restrict__ in_part,
                                             const float* __restrict__ w,
                                             float* __restrict__ out_part,
                                             int init) {
  int tid = threadIdx.x;
  int bid = blockIdx.x;
  int cc = bid & 3;
  int rc = bid >> 2;
  __shared__ float lup[2][RCH];
  __shared__ float lu[RCH];
  int r = tid & 127, h = tid >> 7;
  if (init) {
    if (tid < RCH) lu[tid] = 1.0f / NN;
  } else {
    int i = rc * RCH + r;
    float t = 0.f;
#pragma unroll 8
    for (int p = h * 32; p < h * 32 + 32; p++) t += in_part[(size_t)p * NN + i];
    lup[h][r] = t;
  }
  __syncthreads();
  if (!init && tid < RCH) lu[tid] = w[rc * RCH + tid] / (lup[0][tid] + lup[1][tid]);
  __syncthreads();
  const uint2* m2 = (const uint2*)(mat + (size_t)rc * RCH * NN + (size_t)cc * CCH);
  float a[8] = {0.f, 0.f, 0.f, 0.f, 0.f, 0.f, 0.f, 0.f};
#pragma unroll 16
  for (int rr = 0; rr < RCH; rr++) {
    uint2 q = m2[(size_t)rr * (NN / 8) + tid];
    float ur = lu[rr];
    fma4_fp8(q.x, ur, a);
    fma4_fp8(q.y, ur, a + 4);
  }
  float4* op = (float4*)(out_part + (size_t)rc * NN + cc * CCH + tid * 8);
  op[0] = make_float4(a[0], a[1], a[2], a[3]);
  op[1] = make_float4(a[4], a[5], a[6], a[7]);
}

// ---------------- final u,v from the two partial buffers ----------------
__global__ __launch_bounds__(256) void uv_k(const float* __restrict__ t_part,
                                            const float* __restrict__ s_part,
                                            const float* __restrict__ mu,
                                            const float* __restrict__ nu,
                                            float* __restrict__ uarr,
                                            float* __restrict__ varr) {
  int b = blockIdx.x;
  int i = (b & 31) * 256 + threadIdx.x;
  const float* pp = (b < 32) ? t_part : s_part;
  float t = 0.f;
#pragma unroll 8
  for (int p = 0; p < NPART; p++) t += pp[(size_t)p * NN + i];
  if (b < 32) uarr[i] = mu[i] / t;
  else varr[i] = nu[i] / t;
}

// ---------------- final loss: sum_ij u_i K'_ij M_ij v_j, K' recomputed (exp + fp8 round-trip) ----------------
__global__ __launch_bounds__(256) void loss_k(const float* __restrict__ X, const float* __restrict__ Y,
                                              const float* __restrict__ uarr, const float* __restrict__ varr,
                                              float* __restrict__ part) {
  int tid = threadIdx.x;
  int rb = (int)(blockIdx.x >> 4) * 128;
  int cb = (int)(blockIdx.x & 15) * 512;
  __shared__ float lx[128][DD];
  __shared__ float lx2[128];
  __shared__ float lu[128];
#pragma unroll
  for (int q = 0; q < 4; q++) {
    int idx = tid + q * 256;
    int r = idx >> 3, dq = (idx & 7) * 4;
    float4 vv = *(const float4*)&X[(size_t)(rb + r) * DD + dq];
    lx[r][dq] = vv.x; lx[r][dq + 1] = vv.y; lx[r][dq + 2] = vv.z; lx[r][dq + 3] = vv.w;
  }
  __syncthreads();
  if (tid < 128) {
    float s = 0.f;
#pragma unroll
    for (int d = 0; d < DD; d++) s = fmaf(lx[tid][d], lx[tid][d], s);
    lx2[tid] = s;
    lu[tid] = uarr[rb + tid];
  }
  int j0 = cb + tid * 2;
  float yv0[DD], yv1[DD]; float y20 = 0.f, y21 = 0.f;
#pragma unroll
  for (int dq = 0; dq < DD; dq += 4) {
    float4 a = *(const float4*)&Y[(size_t)j0 * DD + dq];
    float4 b = *(const float4*)&Y[(size_t)(j0 + 1) * DD + dq];
    yv0[dq] = a.x; yv0[dq + 1] = a.y; yv0[dq + 2] = a.z; yv0[dq + 3] = a.w;
    y20 = fmaf(a.x, a.x, fmaf(a.y, a.y, fmaf(a.z, a.z, fmaf(a.w, a.w, y20))));
    yv1[dq] = b.x; yv1[dq + 1] = b.y; yv1[dq + 2] = b.z; yv1[dq + 3] = b.w;
    y21 = fmaf(b.x, b.x, fmaf(b.y, b.y, fmaf(b.z, b.z, fmaf(b.w, b.w, y21))));
  }
  float v0 = varr[j0], v1 = varr[j0 + 1];
  __syncthreads();
  float acc = 0.f;
  for (int r = 0; r < 128; r++) {
    float dot0 = 0.f, dot1 = 0.f;
#pragma unroll
    for (int dq = 0; dq < DD; dq += 4) {
      float4 xx = *(const float4*)&lx[r][dq];
      dot0 = fmaf(xx.x, yv0[dq], fmaf(xx.y, yv0[dq + 1], fmaf(xx.z, yv0[dq + 2], fmaf(xx.w, yv0[dq + 3], dot0))));
      dot1 = fmaf(xx.x, yv1[dq], fmaf(xx.y, yv1[dq + 1], fmaf(xx.z, yv1[dq + 2], fmaf(xx.w, yv1[dq + 3], dot1))));
    }
    float d20 = lx2[r] + y20 - 2.0f * dot0;
    float d21 = lx2[r] + y21 - 2.0f * dot1;
    float M0 = sqrtf(fmaxf(d20, 1e-12f));
    float M1 = sqrtf(fmaxf(d21, 1e-12f));
    float k0 = fminf(__expf(-M0 * REGV_INV) * KSCALE, 448.f);
    float k1 = fminf(__expf(-M1 * REGV_INV) * KSCALE, 448.f);
    uint e = pack4_fp8(k0, k1, 0.f, 0.f);
    vfloat2 kk = __builtin_amdgcn_cvt_pk_f32_fp8(e, false);
    acc = fmaf(lu[r], kk.x * M0 * v0 + kk.y * M1 * v1, acc);
  }
#pragma unroll
  for (int o = 1; o < 64; o <<= 1) acc += __shfl_xor(acc, o);
  __shared__ float r4[4];
  if ((tid & 63) == 0) r4[tid >> 6] = acc;
  __syncthreads();
  if (tid == 0) part[blockIdx.x] = r4[0] + r4[1] + r4[2] + r4[3];
}

__global__ __launch_bounds__(256) void finish_k(const float* __restrict__ part, float* __restrict__ out) {
  int tid = threadIdx.x;
  float s = 0.f;
  for (int k = tid; k < 1024; k += 256) s += part[k];
#pragma unroll
  for (int o = 1; o < 64; o <<= 1) s += __shfl_xor(s, o);
  __shared__ float r4[4];
  if ((tid & 63) == 0) r4[tid >> 6] = s;
  __syncthreads();
  if (tid == 0) out[0] = r4[0] + r4[1] + r4[2] + r4[3];
}

extern "C" void kernel_launch(void* const* d_in, const int* in_sizes, int n_in,
                              void* d_out, int out_size, void* d_ws, size_t ws_size,
                              hipStream_t stream) {
  const float* X = (const float*)d_in[0];
  const float* Y = (const float*)d_in[1];
  const float* sd = (const float*)d_in[2];
  const float* td = (const float*)d_in[3];
  float* out = (float*)d_out;

  char* p = (char*)d_ws;
  uchar* K = (uchar*)p; p += (size_t)NN * NN;          // 67.1 MB
  uchar* KT = (uchar*)p; p += (size_t)NN * NN;         // 67.1 MB
  float* mu = (float*)p; p += (size_t)NN * 4;
  float* nu = (float*)p; p += (size_t)NN * 4;
  float* uarr = (float*)p; p += (size_t)NN * 4;
  float* varr = (float*)p; p += (size_t)NN * 4;
  float* s_part = (float*)p; p += (size_t)NPART * NN * 4;   // 2 MB
  float* t_part = (float*)p; p += (size_t)NPART * NN * 4;   // 2 MB
  float* part = (float*)p;                                   // 4 KB

  softmax_k<<<2, 1024, 0, stream>>>(sd, td, mu, nu);
  build8_k<<<8192, 256, 0, stream>>>(X, Y, K, KT);

  // d even: s_part <- partials of K^T u (u = mu / sum t_part); d odd: t_part <- partials of K v
  for (int d = 0; d < 200; d++) {
    const uchar* mat = (d & 1) ? KT : K;
    const float* w = (d & 1) ? nu : mu;
    const float* inp = (d & 1) ? s_part : t_part;
    float* outp = (d & 1) ? t_part : s_part;
    mv8_k<<<256, 256, 0, stream>>>(mat, inp, w, outp, d == 0 ? 1 : 0);
  }

  uv_k<<<64, 256, 0, stream>>>(t_part, s_part, mu, nu, uarr, varr);
  loss_k<<<1024, 256, 0, stream>>>(X, Y, uarr, varr, part);
  finish_k<<<1, 256, 0, stream>>>(part, out);
}